// Round 3
// baseline (192.767 us; speedup 1.0000x reference)
//
#include <hip/hip_runtime.h>
#include <hip/hip_cooperative_groups.h>

namespace cg = cooperative_groups;

#define TBINS 256
#define NBLK  256
#define NTHR  1024
#define RPB   32          // rows per block in phase 1
#define EPS_F 1e-7f
#define INV_SIGMA 2.0f    // 1/0.5

__global__ __launch_bounds__(NTHR) void fused_kernel(
    const float* __restrict__ hz, const int* __restrict__ dur,
    const int* __restrict__ ev,  const int* __restrict__ lab,
    float* __restrict__ WT, float* __restrict__ B,
    float* __restrict__ nllpart, float* __restrict__ rankpart,
    float* __restrict__ out, int n)
{
    cg::grid_group grid = cg::this_grid();

    __shared__ float trs[RPB][260];    // [local row][t], padded
    __shared__ float nllred[RPB];
    __shared__ float rA[RPB];
    __shared__ float binsG[TBINS];
    __shared__ float binsG0[TBINS];
    __shared__ float scan[TBINS];
    __shared__ float fs[16], fr[16];

    const int blk  = blockIdx.x;
    const int tid  = threadIdx.x;
    const int wid  = tid >> 6;
    const int lane = tid & 63;

    // ======== phase 1: per-row softmax/cdf; W into LDS; nll partials ========
    #pragma unroll
    for (int r = 0; r < 2; ++r) {
        const int lrow = wid * 2 + r;
        const int row  = blk * RPB + lrow;
        const bool act = row < n;
        const int rrow = act ? row : 0;

        const float4 v = ((const float4*)(hz + (size_t)rrow * TBINS))[lane];

        float m = fmaxf(fmaxf(v.x, v.y), fmaxf(v.z, v.w));
        #pragma unroll
        for (int off = 32; off; off >>= 1) m = fmaxf(m, __shfl_xor(m, off));
        const float gamma = fmaxf(m, 0.0f);   // phi has padded 0 column

        const float e0 = expf(v.x - gamma), e1 = expf(v.y - gamma);
        const float e2 = expf(v.z - gamma), e3 = expf(v.w - gamma);
        const float local = e0 + e1 + e2 + e3;

        float pre = local;
        #pragma unroll
        for (int off = 1; off < 64; off <<= 1) {
            float t = __shfl_up(pre, off);
            if (lane >= off) pre += t;
        }
        const float excl  = pre - local;
        const float total = __shfl(pre, 63);
        const float sum_  = total + expf(-gamma);  // padded column exp(0-gamma)
        const float c0 = excl + e0, c1 = c0 + e1, c2 = c1 + e2, c3 = c2 + e3;

        const int L = lab[rrow];
        const int e = ev[rrow];
        const int sel = L & 3;
        float csel = (sel == 0) ? c0 : (sel == 1) ? c1 : (sel == 2) ? c2 : c3;
        const float cum_at = __shfl(csel, L >> 2);
        const float inv = 1.0f / sum_;

        float4 w;
        w.x = expf(c0 * inv * INV_SIGMA);
        w.y = expf(c1 * inv * INV_SIGMA);
        w.z = expf(c2 * inv * INV_SIGMA);
        w.w = expf(c3 * inv * INV_SIGMA);
        *(float4*)&trs[lrow][4 * lane] = w;

        if (lane == 0) {
            float nll_i = 0.f, a_i = 0.f;
            if (act) {
                const float phi_at = hz[(size_t)row * TBINS + L];
                const float evf = (float)e;
                const float p1 = (phi_at - gamma) * evf;
                const float p2 = -logf(fmaxf(sum_, 0.f) + EPS_F);
                const float p3 = logf(fmaxf(sum_ - cum_at, 0.f) + EPS_F) * (1.f - evf);
                nll_i = -(p1 + p2 + p3);
                a_i = e ? expf(-(cum_at * inv) * INV_SIGMA) : 0.f;
            }
            nllred[lrow] = nll_i;
            rA[lrow]     = a_i;
        }
    }
    __syncthreads();

    // transpose out: per t, 8 threads store 32 consecutive i (128B coalesced)
    #pragma unroll
    for (int k = 0; k < 2; ++k) {
        const int t = (tid >> 3) + 128 * k;
        const int j = tid & 7;
        float4 o;
        o.x = trs[4 * j + 0][t];
        o.y = trs[4 * j + 1][t];
        o.z = trs[4 * j + 2][t];
        o.w = trs[4 * j + 3][t];
        const int i0 = blk * RPB + 4 * j;
        if (i0 + 3 < n) *(float4*)&WT[(size_t)t * n + i0] = o;
    }
    if (tid == 0) {
        float s = 0.f;
        #pragma unroll
        for (int k = 0; k < RPB; ++k) s += nllred[k];
        nllpart[blk] = s;
    }
    grid.sync();

    // ======== phase 2: histogram over dur + suffix scan; t = blk ========
    if (tid < TBINS) { binsG[tid] = 0.f; binsG0[tid] = 0.f; }
    __syncthreads();
    {
        const float* wrow = WT + (size_t)blk * n;
        for (int i = tid; i < n; i += NTHR) {
            const float v = wrow[i];
            const int d = dur[i];
            atomicAdd(&binsG[d], v);
            if (ev[i] == 0) atomicAdd(&binsG0[d], v);
        }
    }
    __syncthreads();
    if (tid < TBINS) scan[tid] = binsG[tid];
    __syncthreads();
    for (int off = 1; off < TBINS; off <<= 1) {
        float add = 0.f;
        if (tid < TBINS && tid >= off) add = scan[tid - off];
        __syncthreads();
        if (tid < TBINS) scan[tid] += add;
        __syncthreads();
    }
    if (tid < TBINS)
        B[blk * TBINS + tid] = (scan[TBINS - 1] - scan[tid]) + binsG0[tid];
    grid.sync();

    // ======== phase 3: rank gather for this block's rows ========
    float val = 0.f;
    if (tid < RPB) {
        const int row = blk * RPB + tid;
        if (row < n && ev[row]) val = rA[tid] * B[lab[row] * TBINS + dur[row]];
    }
    if (wid == 0) {
        #pragma unroll
        for (int off = 32; off; off >>= 1) val += __shfl_xor(val, off);
        if (tid == 0) rankpart[blk] = val;
    }
    grid.sync();

    // ======== phase 4: final reduce on block 0 ========
    if (blk == 0) {
        float s  = (tid < NBLK) ? nllpart[tid]  : 0.f;
        float r2 = (tid < NBLK) ? rankpart[tid] : 0.f;
        #pragma unroll
        for (int off = 32; off; off >>= 1) {
            s  += __shfl_xor(s, off);
            r2 += __shfl_xor(r2, off);
        }
        if (lane == 0) { fs[wid] = s; fr[wid] = r2; }
        __syncthreads();
        if (tid == 0) {
            float S = 0.f, R = 0.f;
            #pragma unroll
            for (int k = 0; k < 16; ++k) { S += fs[k]; R += fr[k]; }
            const double nll = (double)S / (double)n;
            const double rl  = (double)R / ((double)n * (double)n);
            out[0] = (float)(0.5 * nll + 0.5 * rl);
        }
    }
}

extern "C" void kernel_launch(void* const* d_in, const int* in_sizes, int n_in,
                              void* d_out, int out_size, void* d_ws, size_t ws_size,
                              hipStream_t stream) {
    const float* hz  = (const float*)d_in[0];
    const int*   dur = (const int*)d_in[1];
    const int*   ev  = (const int*)d_in[2];
    const int*   lab = (const int*)d_in[3];
    float* out = (float*)d_out;

    int n = in_sizes[1];                       // 8192

    float* WT       = (float*)d_ws;            // [TBINS][n]
    float* B        = WT + (size_t)TBINS * n;  // [TBINS][TBINS]
    float* nllpart  = B + TBINS * TBINS;       // [NBLK]
    float* rankpart = nllpart + NBLK;          // [NBLK]

    void* args[] = { (void*)&hz, (void*)&dur, (void*)&ev, (void*)&lab,
                     (void*)&WT, (void*)&B, (void*)&nllpart, (void*)&rankpart,
                     (void*)&out, (void*)&n };
    hipLaunchCooperativeKernel((const void*)fused_kernel,
                               dim3(NBLK), dim3(NTHR), args, 0, stream);
}

// Round 4
// 89.842 us; speedup vs baseline: 2.1456x; 2.1456x over previous
//
#include <hip/hip_runtime.h>
#include <hip/hip_fp16.h>

#define TBINS 256
#define RPB   16         // rows per block in row_kernel (16 waves x 1 row)
#define NTHR  1024
#define EPS_F 1e-7f
#define INV_SIGMA 2.0f   // 1/0.5

// ============ K1: per-row softmax/cdf -> WT (f16, transposed), nll partials ============
__global__ __launch_bounds__(NTHR) void row_kernel(
    const float* __restrict__ hz, const int* __restrict__ dur,
    const int* __restrict__ ev,  const int* __restrict__ lab,
    __half* __restrict__ WT, float* __restrict__ rowA,
    float* __restrict__ nllpart, int n)
{
    __shared__ float trs[RPB][260];   // [local row][t], +4 pad
    __shared__ float nllred[RPB];

    const int wid  = threadIdx.x >> 6;
    const int lane = threadIdx.x & 63;
    const int row  = blockIdx.x * RPB + wid;
    const bool act = row < n;
    const int rrow = act ? row : 0;

    const float4 v = ((const float4*)(hz + (size_t)rrow * TBINS))[lane];

    float m = fmaxf(fmaxf(v.x, v.y), fmaxf(v.z, v.w));
    #pragma unroll
    for (int off = 32; off; off >>= 1) m = fmaxf(m, __shfl_xor(m, off));
    const float gamma = fmaxf(m, 0.0f);         // phi has padded 0 column

    const float e0 = expf(v.x - gamma), e1 = expf(v.y - gamma);
    const float e2 = expf(v.z - gamma), e3 = expf(v.w - gamma);
    const float local = e0 + e1 + e2 + e3;

    float pre = local;
    #pragma unroll
    for (int off = 1; off < 64; off <<= 1) {
        float tv = __shfl_up(pre, off);
        if (lane >= off) pre += tv;
    }
    const float excl  = pre - local;
    const float total = __shfl(pre, 63);
    const float sum_  = total + expf(-gamma);   // padded column exp(0-gamma)
    const float c0 = excl + e0, c1 = c0 + e1, c2 = c1 + e2, c3 = c2 + e3;

    const int L = lab[rrow];
    const int e = ev[rrow];
    const int sel = L & 3;
    float csel = (sel == 0) ? c0 : (sel == 1) ? c1 : (sel == 2) ? c2 : c3;
    const float cum_at = __shfl(csel, L >> 2);
    const float inv = 1.0f / sum_;

    float4 w;
    w.x = expf(c0 * inv * INV_SIGMA);
    w.y = expf(c1 * inv * INV_SIGMA);
    w.z = expf(c2 * inv * INV_SIGMA);
    w.w = expf(c3 * inv * INV_SIGMA);
    *(float4*)&trs[wid][4 * lane] = w;

    if (lane == 0) {
        float nll_i = 0.f, a_i = 0.f;
        if (act) {
            const float phi_at = hz[(size_t)row * TBINS + L];
            const float evf = (float)e;
            const float p1 = (phi_at - gamma) * evf;
            const float p2 = -logf(fmaxf(sum_, 0.f) + EPS_F);
            const float p3 = logf(fmaxf(sum_ - cum_at, 0.f) + EPS_F) * (1.f - evf);
            nll_i = -(p1 + p2 + p3);
            a_i = e ? expf(-(cum_at * inv) * INV_SIGMA) : 0.f;
            rowA[row] = a_i;
        }
        nllred[wid] = nll_i;
    }
    __syncthreads();

    if (threadIdx.x == 0) {
        float s = 0.f;
        #pragma unroll
        for (int k = 0; k < RPB; ++k) s += nllred[k];
        nllpart[blockIdx.x] = s;
    }

    // transpose out: thread -> (t = tid>>2, j = tid&3); write 4 halves (8B)
    const int t  = threadIdx.x >> 2;
    const int j  = threadIdx.x & 3;
    const int i0 = blockIdx.x * RPB + 4 * j;
    if (i0 + 3 < n) {
        ushort4 p;
        p.x = __half_as_ushort(__float2half(trs[4 * j + 0][t]));
        p.y = __half_as_ushort(__float2half(trs[4 * j + 1][t]));
        p.z = __half_as_ushort(__float2half(trs[4 * j + 2][t]));
        p.w = __half_as_ushort(__float2half(trs[4 * j + 3][t]));
        *(ushort4*)&WT[(size_t)t * n + i0] = p;
    }
}

// ============ K2: 512-bin histogram over (dur, ev) + suffix scan -> B ============
// one block per t. B[t][d] = sum_{d'>d} G[t][d'] + G0[t][d]
__global__ __launch_bounds__(NTHR) void agg_kernel(
    const __half* __restrict__ WT, const int* __restrict__ dur,
    const int* __restrict__ ev, float* __restrict__ B, int n)
{
    __shared__ float bins[512];   // [d] for ev==0, [d+256] for ev!=0

    const int t   = blockIdx.x;
    const int tid = threadIdx.x;

    if (tid < 512) bins[tid] = 0.f;
    __syncthreads();

    // 8 contiguous elements per thread: one 16B WT load, 2x int4 dur/ev
    const __half* w = WT + (size_t)t * n;
    const int i0 = tid * 8;
    if (i0 + 7 < n) {
        const ushort4 ha = *(const ushort4*)&w[i0];
        const ushort4 hb = *(const ushort4*)&w[i0 + 4];
        const int4 da = *(const int4*)&dur[i0];
        const int4 db = *(const int4*)&dur[i0 + 4];
        const int4 ea = *(const int4*)&ev[i0];
        const int4 eb = *(const int4*)&ev[i0 + 4];
        atomicAdd(&bins[da.x + (ea.x << 8)], __half2float(__ushort_as_half(ha.x)));
        atomicAdd(&bins[da.y + (ea.y << 8)], __half2float(__ushort_as_half(ha.y)));
        atomicAdd(&bins[da.z + (ea.z << 8)], __half2float(__ushort_as_half(ha.z)));
        atomicAdd(&bins[da.w + (ea.w << 8)], __half2float(__ushort_as_half(ha.w)));
        atomicAdd(&bins[db.x + (eb.x << 8)], __half2float(__ushort_as_half(hb.x)));
        atomicAdd(&bins[db.y + (eb.y << 8)], __half2float(__ushort_as_half(hb.y)));
        atomicAdd(&bins[db.z + (eb.z << 8)], __half2float(__ushort_as_half(hb.z)));
        atomicAdd(&bins[db.w + (eb.w << 8)], __half2float(__ushort_as_half(hb.w)));
    }
    __syncthreads();

    // single-wave suffix scan (no further syncs): lane owns d = 4*lane..4*lane+3
    if (tid < 64) {
        const int d0 = tid * 4;
        const float g0 = bins[d0 + 0] + bins[d0 + 256];
        const float g1 = bins[d0 + 1] + bins[d0 + 257];
        const float g2 = bins[d0 + 2] + bins[d0 + 258];
        const float g3 = bins[d0 + 3] + bins[d0 + 259];
        const float c0 = g0, c1 = c0 + g1, c2 = c1 + g2, c3 = c2 + g3;
        float pre = c3;
        #pragma unroll
        for (int off = 1; off < 64; off <<= 1) {
            float tv = __shfl_up(pre, off);
            if (tid >= off) pre += tv;
        }
        const float excl  = pre - c3;
        const float tot   = __shfl(pre, 63);
        float4 ob;
        ob.x = (tot - (excl + c0)) + bins[d0 + 0];
        ob.y = (tot - (excl + c1)) + bins[d0 + 1];
        ob.z = (tot - (excl + c2)) + bins[d0 + 2];
        ob.w = (tot - (excl + c3)) + bins[d0 + 3];
        *(float4*)&B[t * TBINS + d0] = ob;
    }
}

// ============ K3: rank gather + final combine (one block) ============
__global__ __launch_bounds__(NTHR) void rank_final_kernel(
    const int* __restrict__ dur, const int* __restrict__ lab,
    const float* __restrict__ rowA, const float* __restrict__ B,
    const float* __restrict__ nllpart, float* __restrict__ out,
    int n, int nblk)
{
    const int tid  = threadIdx.x;
    const int wid  = tid >> 6;
    const int lane = tid & 63;
    __shared__ float rs[16], ss[16];

    float r = 0.f;
    for (int i = tid; i < n; i += NTHR) {
        const float a = rowA[i];                 // 0 when ev==0
        if (a != 0.f) r += a * B[lab[i] * TBINS + dur[i]];
    }
    float s = (tid < nblk) ? nllpart[tid] : 0.f;

    #pragma unroll
    for (int off = 32; off; off >>= 1) {
        r += __shfl_xor(r, off);
        s += __shfl_xor(s, off);
    }
    if (lane == 0) { rs[wid] = r; ss[wid] = s; }
    __syncthreads();
    if (tid == 0) {
        float R = 0.f, S = 0.f;
        #pragma unroll
        for (int k = 0; k < 16; ++k) { R += rs[k]; S += ss[k]; }
        const double nll = (double)S / (double)n;
        const double rl  = (double)R / ((double)n * (double)n);
        out[0] = (float)(0.5 * nll + 0.5 * rl);
    }
}

extern "C" void kernel_launch(void* const* d_in, const int* in_sizes, int n_in,
                              void* d_out, int out_size, void* d_ws, size_t ws_size,
                              hipStream_t stream) {
    const float* hz  = (const float*)d_in[0];
    const int*   dur = (const int*)d_in[1];
    const int*   ev  = (const int*)d_in[2];
    const int*   lab = (const int*)d_in[3];
    float* out = (float*)d_out;

    const int n = in_sizes[1];                   // 8192
    const int nblk = (n + RPB - 1) / RPB;        // 512

    __half* WT     = (__half*)d_ws;              // [TBINS][n] f16 (4 MB)
    float*  B      = (float*)(WT + (size_t)TBINS * n);   // [TBINS][TBINS]
    float*  rowA   = B + TBINS * TBINS;          // [n]
    float*  nllpart= rowA + n;                   // [nblk]

    row_kernel<<<nblk, NTHR, 0, stream>>>(hz, dur, ev, lab, WT, rowA, nllpart, n);
    agg_kernel<<<TBINS, NTHR, 0, stream>>>(WT, dur, ev, B, n);
    rank_final_kernel<<<1, NTHR, 0, stream>>>(dur, lab, rowA, B, nllpart, out, n, nblk);
}

// Round 5
// 88.327 us; speedup vs baseline: 2.1824x; 1.0172x over previous
//
#include <hip/hip_runtime.h>
#include <hip/hip_fp16.h>

#define TBINS 256
#define RPB   32         // rows per block in row_kernel (16 waves x 2 rows)
#define NTHR  1024
#define EPS_F 1e-7f
#define INV_SIGMA 2.0f   // 1/0.5

// ============ K1: per-row softmax/cdf -> WT (f16, transposed), nll partials ============
__global__ __launch_bounds__(NTHR) void row_kernel(
    const float* __restrict__ hz, const int* __restrict__ ev,
    const int* __restrict__ lab,
    __half* __restrict__ WT, float* __restrict__ rowA,
    float* __restrict__ nllpart, float* __restrict__ accR, int* __restrict__ done,
    int n)
{
    __shared__ float trs[RPB][261];   // pad 261: transpose reads ~2-way max
    __shared__ float nllred[RPB];

    const int tid  = threadIdx.x;
    const int wid  = tid >> 6;
    const int lane = tid & 63;

    if (blockIdx.x == 0 && tid == 0) { *accR = 0.f; *done = 0; }

    #pragma unroll
    for (int r = 0; r < 2; ++r) {
        const int lrow = wid * 2 + r;
        const int row  = blockIdx.x * RPB + lrow;
        const bool act = row < n;
        const int rrow = act ? row : 0;

        const float4 v = ((const float4*)(hz + (size_t)rrow * TBINS))[lane];

        float m = fmaxf(fmaxf(v.x, v.y), fmaxf(v.z, v.w));
        #pragma unroll
        for (int off = 32; off; off >>= 1) m = fmaxf(m, __shfl_xor(m, off));
        const float gamma = fmaxf(m, 0.0f);        // phi has padded 0 column

        const float e0 = expf(v.x - gamma), e1 = expf(v.y - gamma);
        const float e2 = expf(v.z - gamma), e3 = expf(v.w - gamma);
        const float local = e0 + e1 + e2 + e3;

        float pre = local;
        #pragma unroll
        for (int off = 1; off < 64; off <<= 1) {
            float tv = __shfl_up(pre, off);
            if (lane >= off) pre += tv;
        }
        const float excl  = pre - local;
        const float total = __shfl(pre, 63);
        const float sum_  = total + expf(-gamma);  // padded column exp(0-gamma)
        const float c0 = excl + e0, c1 = c0 + e1, c2 = c1 + e2, c3 = c2 + e3;

        const int L = lab[rrow];
        const int e = ev[rrow];
        const int sel = L & 3;
        float csel = (sel == 0) ? c0 : (sel == 1) ? c1 : (sel == 2) ? c2 : c3;
        const float cum_at = __shfl(csel, L >> 2);
        const float inv = 1.0f / sum_;

        float4 w;
        w.x = expf(c0 * inv * INV_SIGMA);
        w.y = expf(c1 * inv * INV_SIGMA);
        w.z = expf(c2 * inv * INV_SIGMA);
        w.w = expf(c3 * inv * INV_SIGMA);
        *(float4*)&trs[lrow][4 * lane] = w;

        if (lane == 0) {
            float nll_i = 0.f, a_i = 0.f;
            if (act) {
                const float phi_at = hz[(size_t)row * TBINS + L];
                const float evf = (float)e;
                const float p1 = (phi_at - gamma) * evf;
                const float p2 = -logf(fmaxf(sum_, 0.f) + EPS_F);
                const float p3 = logf(fmaxf(sum_ - cum_at, 0.f) + EPS_F) * (1.f - evf);
                nll_i = -(p1 + p2 + p3);
                a_i = e ? expf(-(cum_at * inv) * INV_SIGMA) : 0.f;
                rowA[row] = a_i;
            }
            nllred[lrow] = nll_i;
        }
    }
    __syncthreads();

    if (tid == 0) {
        float s = 0.f;
        #pragma unroll
        for (int k = 0; k < RPB; ++k) s += nllred[k];
        nllpart[blockIdx.x] = s;
    }

    // transpose out: per t, 8 threads cover 32 rows -> 64B contiguous stores
    #pragma unroll
    for (int k = 0; k < 2; ++k) {
        const int t = (tid >> 3) + 128 * k;
        const int j = tid & 7;
        const int i0 = blockIdx.x * RPB + 4 * j;
        if (i0 + 3 < n) {
            ushort4 p;
            p.x = __half_as_ushort(__float2half(trs[4 * j + 0][t]));
            p.y = __half_as_ushort(__float2half(trs[4 * j + 1][t]));
            p.z = __half_as_ushort(__float2half(trs[4 * j + 2][t]));
            p.w = __half_as_ushort(__float2half(trs[4 * j + 3][t]));
            *(ushort4*)&WT[(size_t)t * n + i0] = p;
        }
    }
}

// ============ K2: per-t histogram + suffix scan (LDS) + rank gather + finalize ============
__global__ __launch_bounds__(NTHR) void agg_rank_kernel(
    const __half* __restrict__ WT, const int* __restrict__ dur,
    const int* __restrict__ ev, const int* __restrict__ lab,
    const float* __restrict__ rowA, const float* __restrict__ nllpart,
    float* __restrict__ accR, int* __restrict__ done,
    float* __restrict__ out, int n, int nblk1)
{
    __shared__ float hist[16][512];   // wave-private histograms (32 KB)
    __shared__ float comb[512];
    __shared__ float Brow[TBINS];
    __shared__ float red[16];
    __shared__ int lastflag;

    const int t    = blockIdx.x;
    const int tid  = threadIdx.x;
    const int wid  = tid >> 6;
    const int lane = tid & 63;

    for (int i = tid; i < 16 * 512; i += NTHR) ((float*)hist)[i] = 0.f;
    __syncthreads();

    // histogram: 8 contiguous elements per thread into this wave's private bins
    {
        const __half* w = WT + (size_t)t * n;
        const int i0 = tid * 8;
        if (i0 + 7 < n) {
            const ushort4 ha = *(const ushort4*)&w[i0];
            const ushort4 hb = *(const ushort4*)&w[i0 + 4];
            const int4 da = *(const int4*)&dur[i0];
            const int4 db = *(const int4*)&dur[i0 + 4];
            const int4 ea = *(const int4*)&ev[i0];
            const int4 eb = *(const int4*)&ev[i0 + 4];
            float* hb_ = hist[wid];
            atomicAdd(&hb_[da.x + (ea.x << 8)], __half2float(__ushort_as_half(ha.x)));
            atomicAdd(&hb_[da.y + (ea.y << 8)], __half2float(__ushort_as_half(ha.y)));
            atomicAdd(&hb_[da.z + (ea.z << 8)], __half2float(__ushort_as_half(ha.z)));
            atomicAdd(&hb_[da.w + (ea.w << 8)], __half2float(__ushort_as_half(ha.w)));
            atomicAdd(&hb_[db.x + (eb.x << 8)], __half2float(__ushort_as_half(hb.x)));
            atomicAdd(&hb_[db.y + (eb.y << 8)], __half2float(__ushort_as_half(hb.y)));
            atomicAdd(&hb_[db.z + (eb.z << 8)], __half2float(__ushort_as_half(hb.z)));
            atomicAdd(&hb_[db.w + (eb.w << 8)], __half2float(__ushort_as_half(hb.w)));
        }
    }
    __syncthreads();

    // combine 16 wave-private histograms
    if (tid < 512) {
        float s = 0.f;
        #pragma unroll
        for (int k = 0; k < 16; ++k) s += hist[k][tid];
        comb[tid] = s;
    }
    __syncthreads();

    // single-wave suffix scan: bin d (ev==0 -> G0 at [d], ev==1 at [d+256])
    if (tid < 64) {
        const int d0 = tid * 4;
        const float g0 = comb[d0 + 0] + comb[d0 + 256];
        const float g1 = comb[d0 + 1] + comb[d0 + 257];
        const float g2 = comb[d0 + 2] + comb[d0 + 258];
        const float g3 = comb[d0 + 3] + comb[d0 + 259];
        const float c0 = g0, c1 = c0 + g1, c2 = c1 + g2, c3 = c2 + g3;
        float pre = c3;
        #pragma unroll
        for (int off = 1; off < 64; off <<= 1) {
            float tv = __shfl_up(pre, off);
            if (tid >= off) pre += tv;
        }
        const float excl = pre - c3;
        const float tot  = __shfl(pre, 63);
        Brow[d0 + 0] = (tot - (excl + c0)) + comb[d0 + 0];
        Brow[d0 + 1] = (tot - (excl + c1)) + comb[d0 + 1];
        Brow[d0 + 2] = (tot - (excl + c2)) + comb[d0 + 2];
        Brow[d0 + 3] = (tot - (excl + c3)) + comb[d0 + 3];
    }
    __syncthreads();

    // rank gather: rows with lab == t use Brow (resident in LDS)
    float val = 0.f;
    {
        const int i0 = tid * 8;
        if (i0 + 7 < n) {
            const int4 la = *(const int4*)&lab[i0];
            const int4 lb = *(const int4*)&lab[i0 + 4];
            const int ls[8] = { la.x, la.y, la.z, la.w, lb.x, lb.y, lb.z, lb.w };
            #pragma unroll
            for (int k = 0; k < 8; ++k) {
                if (ls[k] == t) {
                    const float a = rowA[i0 + k];      // 0 when ev==0
                    if (a != 0.f) val += a * Brow[dur[i0 + k]];
                }
            }
        }
    }
    #pragma unroll
    for (int off = 32; off; off >>= 1) val += __shfl_xor(val, off);
    if (lane == 0) red[wid] = val;
    __syncthreads();

    if (tid == 0) {
        float s = 0.f;
        #pragma unroll
        for (int k = 0; k < 16; ++k) s += red[k];
        atomicAdd(accR, s);
        __threadfence();
        const int old = atomicAdd(done, 1);
        lastflag = (old == (int)gridDim.x - 1) ? 1 : 0;
    }
    __syncthreads();

    // last block finalizes: reduce nll partials + combine
    if (lastflag) {
        float s = (tid < nblk1) ? nllpart[tid] : 0.f;
        #pragma unroll
        for (int off = 32; off; off >>= 1) s += __shfl_xor(s, off);
        if (lane == 0) red[wid] = s;
        __syncthreads();
        if (tid == 0) {
            float S = 0.f;
            #pragma unroll
            for (int k = 0; k < 16; ++k) S += red[k];
            __threadfence();
            const float R = atomicAdd(accR, 0.0f);   // coherent read
            const double nll = (double)S / (double)n;
            const double rl  = (double)R / ((double)n * (double)n);
            out[0] = (float)(0.5 * nll + 0.5 * rl);
        }
    }
}

extern "C" void kernel_launch(void* const* d_in, const int* in_sizes, int n_in,
                              void* d_out, int out_size, void* d_ws, size_t ws_size,
                              hipStream_t stream) {
    const float* hz  = (const float*)d_in[0];
    const int*   dur = (const int*)d_in[1];
    const int*   ev  = (const int*)d_in[2];
    const int*   lab = (const int*)d_in[3];
    float* out = (float*)d_out;

    const int n = in_sizes[1];                   // 8192
    const int nblk1 = (n + RPB - 1) / RPB;       // 256

    __half* WT      = (__half*)d_ws;             // [TBINS][n] f16 (4 MB)
    float*  rowA    = (float*)(WT + (size_t)TBINS * n);
    float*  nllpart = rowA + n;                  // [nblk1]
    float*  accR    = nllpart + nblk1;           // rank accumulator
    int*    done    = (int*)(accR + 1);          // completion counter

    row_kernel<<<nblk1, NTHR, 0, stream>>>(hz, ev, lab, WT, rowA, nllpart, accR, done, n);
    agg_rank_kernel<<<TBINS, NTHR, 0, stream>>>(WT, dur, ev, lab, rowA, nllpart,
                                                accR, done, out, n, nblk1);
}